// Round 2
// baseline (229.024 us; speedup 1.0000x reference)
//
#include <hip/hip_runtime.h>

#define S_LEN 2048
#define D_DIM 128
#define BM 128
#define BN 64
#define NQT (S_LEN / BM)   // 16

typedef __attribute__((ext_vector_type(8))) short short8;
typedef __attribute__((ext_vector_type(4))) float floatx4;
typedef __attribute__((ext_vector_type(4))) unsigned uintx4;
typedef unsigned short u16;

__device__ __forceinline__ u16 f2b(float f) {
    union { float f; unsigned u; } x; x.f = f;
    unsigned r = x.u + 0x7FFFu + ((x.u >> 16) & 1u);  // RNE
    return (u16)(r >> 16);
}
__device__ __forceinline__ float b2f(u16 h) {
    union { unsigned u; float f; } x; x.u = ((unsigned)h) << 16;
    return x.f;
}
__device__ __forceinline__ void gld_lds16(const void* g, void* l) {
    __builtin_amdgcn_global_load_lds(
        (const __attribute__((address_space(1))) unsigned int*)g,
        (__attribute__((address_space(3))) unsigned int*)l, 16, 0, 0);
}
__device__ __forceinline__ floatx4 mfma16(short8 a, short8 b, floatx4 c) {
    return __builtin_amdgcn_mfma_f32_16x16x32_bf16(a, b, c, 0, 0, 0);
}

// ---------------- fused pre-pass: K fp32->bf16 (x<32) | V transpose (x>=32) ----
// Verified correct in r4/r5 (absmax 0.0156). UNCHANGED.
__global__ __launch_bounds__(256) void prep_kv(const float* __restrict__ k,
                                               const float* __restrict__ v,
                                               u16* __restrict__ kw,
                                               u16* __restrict__ vt) {
    const int x   = blockIdx.x;
    const int bh  = blockIdx.y;
    const int tid = threadIdx.x;
    if (x < 32) {
        const float* src = k + (size_t)bh * S_LEN * D_DIM + (size_t)x * 8192;
        u16* dst = kw + (size_t)bh * S_LEN * D_DIM + (size_t)x * 8192;
        #pragma unroll
        for (int i = 0; i < 8; ++i) {
            int e = i * 1024 + tid * 4;
            float4 xx = *(const float4*)(src + e);
            ushort4 h;
            h.x = f2b(xx.x); h.y = f2b(xx.y); h.z = f2b(xx.z); h.w = f2b(xx.w);
            *(ushort4*)(dst + e) = h;
        }
    } else {
        __shared__ float T[64][65];
        const int t  = x - 32;           // 0..63
        const int s0 = (t >> 1) * 64;
        const int d0 = (t & 1) * 64;
        const float* vb = v + ((size_t)bh * S_LEN + s0) * D_DIM + d0;
        #pragma unroll
        for (int i = 0; i < 4; ++i) {
            int unit = i * 256 + tid;
            int s = unit >> 4;
            int c = (unit & 15) * 4;
            float4 xx = *(const float4*)(vb + s * D_DIM + c);
            T[s][c + 0] = xx.x; T[s][c + 1] = xx.y;
            T[s][c + 2] = xx.z; T[s][c + 3] = xx.w;
        }
        __syncthreads();
        u16* ob = vt + (size_t)bh * D_DIM * S_LEN + (size_t)d0 * S_LEN + s0;
        #pragma unroll
        for (int i = 0; i < 4; ++i) {
            int unit = i * 256 + tid;
            int d  = unit >> 4;
            int sl = (unit & 15) * 4;
            ushort4 h;
            h.x = f2b(T[sl + 0][d]); h.y = f2b(T[sl + 1][d]);
            h.z = f2b(T[sl + 2][d]); h.w = f2b(T[sl + 3][d]);
            *(ushort4*)(ob + (size_t)d * S_LEN + sl) = h;
        }
    }
}

// ---------------- monolithic flash kernel, transposed-S, dbuf staging ----------
// r7: (A) cross-phase ILP — hoist 8 of 16 V ds_read_b128 before the softmax
// phase (LDS pipe drains V under the VALU phase); tree-shape the fmax / rs
// reduction chains (depth 16 -> 4/6).  (B) XCD-grouped block mapping: XCD
// x (= blockIdx%8 under round-robin dispatch) owns bh in {4x..4x+3} so each
// XCD's 4MB L2 holds its K/V working set (cuts the 56MB K/V HBM re-fetch and
// the ~900cyc staged-load misses at the per-iter barrier drain). Preserves the
// verified complementary (qt,15-qt) same-CU pairing: blocks n and n+256 have
// identical x,bh and paired qt (sum NT = 36, uniform per CU).
__global__ __launch_bounds__(512, 4) void fa_main(const float* __restrict__ q,
                                                  const u16* __restrict__ kw,
                                                  const u16* __restrict__ vtw,
                                                  float* __restrict__ out) {
    __shared__ u16 Ks[2][BN * D_DIM];   // XOR-swizzled granules
    __shared__ u16 Vt[2][D_DIM * BN];   // XOR-swizzled granules

    // XCD-grouped + complementary-pair mapping (bijective: 512 = 8*8*2*4)
    const int n  = blockIdx.x;
    const int x  = n & 7;          // XCD under round-robin dispatch
    const int s  = n >> 3;         // 0..63
    const int hi = s >> 5;
    const int r  = s & 31;
    const int bh = x * 4 + (r >> 3);       // 4 bh per XCD -> K/V fits 4MB L2
    const int iq = r & 7;
    const int qt = hi ? iq : (15 - iq);    // pair (15-i, i) on same CU

    const int q0   = qt * BM;
    const int tid  = threadIdx.x;
    const int w    = tid >> 6;       // 0..7
    const int lane = tid & 63;
    const int ln   = lane & 15;
    const int quad = lane >> 4;
    constexpr float qs = 0.08838834764831845f * 1.44269504088896340f;
    const int rowb0 = q0 + w * 16;   // this wave's 16 q-rows: rowb0 + ln

    // ---- Q fragments (B-operand; layout identical to A), scale*log2e folded ----
    short8 qf[4];
    {
        const float* qrow = q + ((size_t)bh * S_LEN + rowb0 + ln) * D_DIM;
        #pragma unroll
        for (int kc = 0; kc < 4; ++kc) {
            const float* p = qrow + kc * 32 + quad * 8;
            float4 x0 = *(const float4*)(p);
            float4 x1 = *(const float4*)(p + 4);
            short8 f;
            f[0] = (short)f2b(x0.x * qs); f[1] = (short)f2b(x0.y * qs);
            f[2] = (short)f2b(x0.z * qs); f[3] = (short)f2b(x0.w * qs);
            f[4] = (short)f2b(x1.x * qs); f[5] = (short)f2b(x1.y * qs);
            f[6] = (short)f2b(x1.z * qs); f[7] = (short)f2b(x1.w * qs);
            qf[kc] = f;
        }
    }

    floatx4 o[8];   // O^T accs: col=ln=qrow, row=quad*4+reg = d within db-block
    #pragma unroll
    for (int db = 0; db < 8; ++db) o[db] = (floatx4){0.f, 0.f, 0.f, 0.f};
    float m_i = -1e30f;
    float l_i = 0.f;

    const u16* kb_bh = kw + (size_t)bh * S_LEN * D_DIM;
    const u16* vb_bh = vtw + (size_t)bh * D_DIM * S_LEN;
    const int NT = 2 * qt + 2;

    auto stage = [&](int t, int b) {
        const int n0 = t * BN;
        const u16* kb = kb_bh + (size_t)n0 * D_DIM;
        #pragma unroll
        for (int i = 0; i < 2; ++i) {
            int R0 = w * 8 + i * 4;            // 8 waves x 2 calls x 4 rows = 64
            int rr = R0 + (lane >> 4);
            int p = lane & 15;
            gld_lds16(kb + rr * D_DIM + ((p ^ (rr & 7)) << 3), &Ks[b][R0 * D_DIM]);
        }
        #pragma unroll
        for (int i = 0; i < 2; ++i) {
            int D0 = (w * 2 + i) * 8;          // 8 waves x 2 calls x 8 rows = 128
            int d = D0 + (lane >> 3);
            int p = lane & 7;
            gld_lds16(vb_bh + (size_t)d * S_LEN + n0 + ((p ^ (d & 7)) << 3),
                      &Vt[b][D0 * BN]);
        }
    };

    stage(0, 0);

    for (int t = 0; t < NT; ++t) {
        __syncthreads();                       // buf[t&1] staged (drain hidden)
        if (t + 1 < NT) stage(t + 1, (t + 1) & 1);   // prefetch next tile
        const u16* ks = Ks[t & 1];
        const u16* vs = Vt[t & 1];
        const int n0 = t * BN;
        if (n0 > rowb0 + 15) continue;         // wave-uniform: fully masked tile

        // ---- S^T = K Q^T : col=ln=qrow, row=quad*4+reg = kv within nb-block ----
        floatx4 sc[4];
        #pragma unroll
        for (int nb = 0; nb < 4; ++nb) {
            short8 kf[4];
            #pragma unroll
            for (int kc = 0; kc < 4; ++kc) {
                int rr = nb * 16 + ln;
                kf[kc] = *(const short8*)&ks[rr * D_DIM + (((kc * 4 + quad) ^ (rr & 7)) << 3)];
            }
            floatx4 a = (floatx4){0.f, 0.f, 0.f, 0.f};
            #pragma unroll
            for (int kc = 0; kc < 4; ++kc) a = mfma16(kf[kc], qf[kc], a);
            sc[nb] = a;
        }

        // ---- preload V rows for db 0..3 NOW: LDS pipe runs under softmax VALU --
        short8 vfr[8];
        #pragma unroll
        for (int db = 0; db < 4; ++db) {
            int d = db * 16 + ln;
            vfr[2 * db + 0] = *(const short8*)&vs[d * BN + ((quad ^ (d & 7)) << 3)];
            vfr[2 * db + 1] = *(const short8*)&vs[d * BN + (((4 + quad) ^ (d & 7)) << 3)];
        }

        // ---- mask, online softmax (scalar state), B-frag build ----
        const int qrow = rowb0 + ln;
        if (n0 + 63 > rowb0) {   // diagonal region: elementwise causal mask
            #pragma unroll
            for (int nb = 0; nb < 4; ++nb) {
                int kvb = n0 + nb * 16 + quad * 4;
                #pragma unroll
                for (int rr = 0; rr < 4; ++rr)
                    if (kvb + rr > qrow) sc[nb][rr] = -1e30f;
            }
        }
        // tree max over 16 in-lane (depth 4, max3-fusable) + 2 shfls
        float mx;
        {
            floatx4 m01, m23;
            #pragma unroll
            for (int rr = 0; rr < 4; ++rr) {
                m01[rr] = fmaxf(sc[0][rr], sc[1][rr]);
                m23[rr] = fmaxf(sc[2][rr], sc[3][rr]);
            }
            floatx4 mm;
            #pragma unroll
            for (int rr = 0; rr < 4; ++rr) mm[rr] = fmaxf(m01[rr], m23[rr]);
            mx = fmaxf(fmaxf(mm[0], mm[1]), fmaxf(mm[2], mm[3]));
        }
        mx = fmaxf(mx, __shfl_xor(mx, 16));
        mx = fmaxf(mx, __shfl_xor(mx, 32));
        float mn = fmaxf(m_i, mx);
        float al = __builtin_amdgcn_exp2f(m_i - mn);
        m_i = mn;
        float rsn[4];
        unsigned pk0[4], pk1[4];
        #pragma unroll
        for (int nb = 0; nb < 4; ++nb) {
            u16 h[4];
            #pragma unroll
            for (int rr = 0; rr < 4; ++rr) {
                float p = __builtin_amdgcn_exp2f(sc[nb][rr] - mn);
                h[rr] = f2b(p);
            }
            // rounded values: num/denom consistent; pairwise tree (depth 2)
            rsn[nb] = (b2f(h[0]) + b2f(h[1])) + (b2f(h[2]) + b2f(h[3]));
            pk0[nb] = (unsigned)h[0] | ((unsigned)h[1] << 16);
            pk1[nb] = (unsigned)h[2] | ((unsigned)h[3] << 16);
        }
        float rs = (rsn[0] + rsn[1]) + (rsn[2] + rsn[3]);
        rs += __shfl_xor(rs, 16);
        rs += __shfl_xor(rs, 32);
        l_i = l_i * al + rs;
        #pragma unroll
        for (int db = 0; db < 8; ++db) o[db] *= al;

        // B-frag (K=32) for kv-block p: lane(q,ln) needs kv=32p+8q+j.
        // src: nb=2p+(q>>1), src quads {2(q&1), 2(q&1)+1}.
        short8 bfr[2];
        const int s0l = ((quad & 1) << 5) + ln;   // src lane: quad 2*(q&1), same ln
        const int s1l = s0l + 16;                 // src lane: quad 2*(q&1)+1
        const bool hiq = (quad >> 1) != 0;
        #pragma unroll
        for (int p = 0; p < 2; ++p) {
            unsigned l0 = __shfl((int)pk0[2 * p], s0l), h0 = __shfl((int)pk0[2 * p + 1], s0l);
            unsigned l1 = __shfl((int)pk1[2 * p], s0l), h1 = __shfl((int)pk1[2 * p + 1], s0l);
            unsigned l2 = __shfl((int)pk0[2 * p], s1l), h2 = __shfl((int)pk0[2 * p + 1], s1l);
            unsigned l3 = __shfl((int)pk1[2 * p], s1l), h3 = __shfl((int)pk1[2 * p + 1], s1l);
            union { uintx4 u; short8 s; } bc;
            bc.u = (uintx4){hiq ? h0 : l0, hiq ? h1 : l1, hiq ? h2 : l2, hiq ? h3 : l3};
            bfr[p] = bc.s;
        }

        // ---- O^T += V^T P^T : db 0..3 from preloaded regs, db 4..7 inline ----
        #pragma unroll
        for (int db = 0; db < 4; ++db) {
            o[db] = mfma16(vfr[2 * db + 0], bfr[0], o[db]);
            o[db] = mfma16(vfr[2 * db + 1], bfr[1], o[db]);
        }
        #pragma unroll
        for (int db = 4; db < 8; ++db) {
            int d = db * 16 + ln;
            short8 v0 = *(const short8*)&vs[d * BN + ((quad ^ (d & 7)) << 3)];
            short8 v1 = *(const short8*)&vs[d * BN + (((4 + quad) ^ (d & 7)) << 3)];
            o[db] = mfma16(v0, bfr[0], o[db]);
            o[db] = mfma16(v1, bfr[1], o[db]);
        }
    }

    // ---- epilogue: O = (O^T)^T / l ; lane ln owns qrow, regs are d ----
    {
        float inv = 1.f / l_i;
        size_t row = (size_t)bh * S_LEN + rowb0 + ln;
        float* orow = out + row * D_DIM + quad * 4;
        #pragma unroll
        for (int db = 0; db < 8; ++db) {
            float4 st = {o[db][0] * inv, o[db][1] * inv,
                         o[db][2] * inv, o[db][3] * inv};
            *(float4*)(orow + db * 16) = st;
        }
    }
}

extern "C" void kernel_launch(void* const* d_in, const int* in_sizes, int n_in,
                              void* d_out, int out_size, void* d_ws, size_t ws_size,
                              hipStream_t stream) {
    const float* q = (const float*)d_in[0];
    const float* k = (const float*)d_in[1];
    const float* v = (const float*)d_in[2];
    float* out = (float*)d_out;
    const int bh = in_sizes[0] / (S_LEN * D_DIM);     // 32
    const size_t kelems = (size_t)bh * S_LEN * D_DIM; // 8.39M

    u16* kw = (u16*)d_ws;
    u16* vt = kw + kelems;
    prep_kv<<<dim3(96, bh), 256, 0, stream>>>(k, v, kw, vt);
    fa_main<<<dim3(NQT * bh), 512, 0, stream>>>(q, kw, vt, out);
}

// Round 4
// 199.151 us; speedup vs baseline: 1.1500x; 1.1500x over previous
//
#include <hip/hip_runtime.h>

#define S_LEN 2048
#define D_DIM 128
#define BM 128
#define BN 64
#define NQT (S_LEN / BM)   // 16

typedef __attribute__((ext_vector_type(8))) short short8;
typedef __attribute__((ext_vector_type(4))) float floatx4;
typedef __attribute__((ext_vector_type(4))) unsigned uintx4;
typedef unsigned short u16;

__device__ __forceinline__ u16 f2b(float f) {
    union { float f; unsigned u; } x; x.f = f;
    unsigned r = x.u + 0x7FFFu + ((x.u >> 16) & 1u);  // RNE
    return (u16)(r >> 16);
}
__device__ __forceinline__ float b2f(u16 h) {
    union { unsigned u; float f; } x; x.u = ((unsigned)h) << 16;
    return x.f;
}
__device__ __forceinline__ void gld_lds16(const void* g, void* l) {
    __builtin_amdgcn_global_load_lds(
        (const __attribute__((address_space(1))) unsigned int*)g,
        (__attribute__((address_space(3))) unsigned int*)l, 16, 0, 0);
}
__device__ __forceinline__ floatx4 mfma16(short8 a, short8 b, floatx4 c) {
    return __builtin_amdgcn_mfma_f32_16x16x32_bf16(a, b, c, 0, 0, 0);
}

// ---------------- fused pre-pass: K fp32->bf16 (x<32) | V transpose (x>=32) ----
// Verified correct in r4/r5 (absmax 0.0156). UNCHANGED.
__global__ __launch_bounds__(256) void prep_kv(const float* __restrict__ k,
                                               const float* __restrict__ v,
                                               u16* __restrict__ kw,
                                               u16* __restrict__ vt) {
    const int x   = blockIdx.x;
    const int bh  = blockIdx.y;
    const int tid = threadIdx.x;
    if (x < 32) {
        const float* src = k + (size_t)bh * S_LEN * D_DIM + (size_t)x * 8192;
        u16* dst = kw + (size_t)bh * S_LEN * D_DIM + (size_t)x * 8192;
        #pragma unroll
        for (int i = 0; i < 8; ++i) {
            int e = i * 1024 + tid * 4;
            float4 xx = *(const float4*)(src + e);
            ushort4 h;
            h.x = f2b(xx.x); h.y = f2b(xx.y); h.z = f2b(xx.z); h.w = f2b(xx.w);
            *(ushort4*)(dst + e) = h;
        }
    } else {
        __shared__ float T[64][65];
        const int t  = x - 32;           // 0..63
        const int s0 = (t >> 1) * 64;
        const int d0 = (t & 1) * 64;
        const float* vb = v + ((size_t)bh * S_LEN + s0) * D_DIM + d0;
        #pragma unroll
        for (int i = 0; i < 4; ++i) {
            int unit = i * 256 + tid;
            int s = unit >> 4;
            int c = (unit & 15) * 4;
            float4 xx = *(const float4*)(vb + s * D_DIM + c);
            T[s][c + 0] = xx.x; T[s][c + 1] = xx.y;
            T[s][c + 2] = xx.z; T[s][c + 3] = xx.w;
        }
        __syncthreads();
        u16* ob = vt + (size_t)bh * D_DIM * S_LEN + (size_t)d0 * S_LEN + s0;
        #pragma unroll
        for (int i = 0; i < 4; ++i) {
            int unit = i * 256 + tid;
            int d  = unit >> 4;
            int sl = (unit & 15) * 4;
            ushort4 h;
            h.x = f2b(T[sl + 0][d]); h.y = f2b(T[sl + 1][d]);
            h.z = f2b(T[sl + 2][d]); h.w = f2b(T[sl + 3][d]);
            *(ushort4*)(ob + (size_t)d * S_LEN + sl) = h;
        }
    }
}

// ---------------- monolithic flash kernel, transposed-S, dbuf staging ----------
// r9 == r8 resubmit (r8 bench died on container acquisition, not the kernel):
// r8: REVERT both r7 changes (back to the proven r6/92µs structure):
//   - r6 block mapping restored (XCD-grouping caused lockstep same-address L2
//     streams; r6's higher HBM fetch was hidden anyway).
//   - PV V-reads back inline (the r7 preload put 8 outstanding ds_reads ahead
//     of the softmax shfls on the IN-ORDER lgkm counter, lengthening the
//     serial max-reduce path).
// ADD: T13 deferred rescale (threshold 8): skip al=exp2 / m_i update /
// l_i*=al / 32-instr o-rescale when __all(mx <= m_i+8). P bounded by e^8;
// bf16 relative precision unchanged; final /l normalizes. First tile always
// rescales (m_i=-1e30). Tree-shaped max/sum reductions kept from r7.
__global__ __launch_bounds__(512, 4) void fa_main(const float* __restrict__ q,
                                                  const u16* __restrict__ kw,
                                                  const u16* __restrict__ vtw,
                                                  float* __restrict__ out) {
    __shared__ u16 Ks[2][BN * D_DIM];   // XOR-swizzled granules
    __shared__ u16 Vt[2][D_DIM * BN];   // XOR-swizzled granules

    // complementary-pair balanced mapping (r5/r6, verified): per-CU work uniform
    const int n  = blockIdx.x;
    const int hi = n >> 8;
    const int ii = n & 255;
    const int qt = hi ? (ii & 15) : 15 - (ii & 15);
    const int bh = hi * 16 + (ii >> 4);

    const int q0   = qt * BM;
    const int tid  = threadIdx.x;
    const int w    = tid >> 6;       // 0..7
    const int lane = tid & 63;
    const int ln   = lane & 15;
    const int quad = lane >> 4;
    constexpr float qs = 0.08838834764831845f * 1.44269504088896340f;
    const int rowb0 = q0 + w * 16;   // this wave's 16 q-rows: rowb0 + ln

    // ---- Q fragments (B-operand; layout identical to A), scale*log2e folded ----
    short8 qf[4];
    {
        const float* qrow = q + ((size_t)bh * S_LEN + rowb0 + ln) * D_DIM;
        #pragma unroll
        for (int kc = 0; kc < 4; ++kc) {
            const float* p = qrow + kc * 32 + quad * 8;
            float4 x0 = *(const float4*)(p);
            float4 x1 = *(const float4*)(p + 4);
            short8 f;
            f[0] = (short)f2b(x0.x * qs); f[1] = (short)f2b(x0.y * qs);
            f[2] = (short)f2b(x0.z * qs); f[3] = (short)f2b(x0.w * qs);
            f[4] = (short)f2b(x1.x * qs); f[5] = (short)f2b(x1.y * qs);
            f[6] = (short)f2b(x1.z * qs); f[7] = (short)f2b(x1.w * qs);
            qf[kc] = f;
        }
    }

    floatx4 o[8];   // O^T accs: col=ln=qrow, row=quad*4+reg = d within db-block
    #pragma unroll
    for (int db = 0; db < 8; ++db) o[db] = (floatx4){0.f, 0.f, 0.f, 0.f};
    float m_i = -1e30f;
    float l_i = 0.f;

    const u16* kb_bh = kw + (size_t)bh * S_LEN * D_DIM;
    const u16* vb_bh = vtw + (size_t)bh * D_DIM * S_LEN;
    const int NT = 2 * qt + 2;

    auto stage = [&](int t, int b) {
        const int n0 = t * BN;
        const u16* kb = kb_bh + (size_t)n0 * D_DIM;
        #pragma unroll
        for (int i = 0; i < 2; ++i) {
            int R0 = w * 8 + i * 4;            // 8 waves x 2 calls x 4 rows = 64
            int r = R0 + (lane >> 4);
            int p = lane & 15;
            gld_lds16(kb + r * D_DIM + ((p ^ (r & 7)) << 3), &Ks[b][R0 * D_DIM]);
        }
        #pragma unroll
        for (int i = 0; i < 2; ++i) {
            int D0 = (w * 2 + i) * 8;          // 8 waves x 2 calls x 8 rows = 128
            int d = D0 + (lane >> 3);
            int p = lane & 7;
            gld_lds16(vb_bh + (size_t)d * S_LEN + n0 + ((p ^ (d & 7)) << 3),
                      &Vt[b][D0 * BN]);
        }
    };

    stage(0, 0);

    for (int t = 0; t < NT; ++t) {
        __syncthreads();                       // buf[t&1] staged (drain hidden)
        if (t + 1 < NT) stage(t + 1, (t + 1) & 1);   // prefetch next tile
        const u16* ks = Ks[t & 1];
        const u16* vs = Vt[t & 1];
        const int n0 = t * BN;
        if (n0 > rowb0 + 15) continue;         // wave-uniform: fully masked tile

        // ---- S^T = K Q^T : col=ln=qrow, row=quad*4+reg = kv within nb-block ----
        floatx4 sc[4];
        #pragma unroll
        for (int nb = 0; nb < 4; ++nb) {
            short8 kf[4];
            #pragma unroll
            for (int kc = 0; kc < 4; ++kc) {
                int r = nb * 16 + ln;
                kf[kc] = *(const short8*)&ks[r * D_DIM + (((kc * 4 + quad) ^ (r & 7)) << 3)];
            }
            floatx4 a = (floatx4){0.f, 0.f, 0.f, 0.f};
            #pragma unroll
            for (int kc = 0; kc < 4; ++kc) a = mfma16(kf[kc], qf[kc], a);
            sc[nb] = a;
        }

        // ---- mask, online softmax (deferred-rescale), B-frag build ----
        const int qrow = rowb0 + ln;
        if (n0 + 63 > rowb0) {   // diagonal region: elementwise causal mask
            #pragma unroll
            for (int nb = 0; nb < 4; ++nb) {
                int kvb = n0 + nb * 16 + quad * 4;
                #pragma unroll
                for (int r = 0; r < 4; ++r)
                    if (kvb + r > qrow) sc[nb][r] = -1e30f;
            }
        }
        // tree max over 16 in-lane (depth 4, max3-fusable) + 2 shfls
        float mx;
        {
            floatx4 m01, m23;
            #pragma unroll
            for (int r = 0; r < 4; ++r) {
                m01[r] = fmaxf(sc[0][r], sc[1][r]);
                m23[r] = fmaxf(sc[2][r], sc[3][r]);
            }
            floatx4 mm;
            #pragma unroll
            for (int r = 0; r < 4; ++r) mm[r] = fmaxf(m01[r], m23[r]);
            mx = fmaxf(fmaxf(mm[0], mm[1]), fmaxf(mm[2], mm[3]));
        }
        mx = fmaxf(mx, __shfl_xor(mx, 16));
        mx = fmaxf(mx, __shfl_xor(mx, 32));
        // T13: defer rescale while max growth <= 8 (P bounded by e^8)
        if (!__all(mx <= m_i + 8.f)) {
            float mn = fmaxf(m_i, mx);
            float al = __builtin_amdgcn_exp2f(m_i - mn);
            m_i = mn;
            l_i *= al;
            #pragma unroll
            for (int db = 0; db < 8; ++db) o[db] *= al;
        }
        const float mn = m_i;
        float rsn[4];
        unsigned pk0[4], pk1[4];
        #pragma unroll
        for (int nb = 0; nb < 4; ++nb) {
            u16 h[4];
            #pragma unroll
            for (int r = 0; r < 4; ++r) {
                float p = __builtin_amdgcn_exp2f(sc[nb][r] - mn);
                h[r] = f2b(p);
            }
            // rounded values: num/denom consistent; pairwise tree
            rsn[nb] = (b2f(h[0]) + b2f(h[1])) + (b2f(h[2]) + b2f(h[3]));
            pk0[nb] = (unsigned)h[0] | ((unsigned)h[1] << 16);
            pk1[nb] = (unsigned)h[2] | ((unsigned)h[3] << 16);
        }
        float rs = (rsn[0] + rsn[1]) + (rsn[2] + rsn[3]);
        rs += __shfl_xor(rs, 16);
        rs += __shfl_xor(rs, 32);
        l_i += rs;

        // B-frag (K=32) for kv-block p: lane(q,ln) needs kv=32p+8q+j.
        // src: nb=2p+(q>>1), src quads {2(q&1), 2(q&1)+1}.
        short8 bfr[2];
        const int s0l = ((quad & 1) << 5) + ln;   // src lane: quad 2*(q&1), same ln
        const int s1l = s0l + 16;                 // src lane: quad 2*(q&1)+1
        const bool hiq = (quad >> 1) != 0;
        #pragma unroll
        for (int p = 0; p < 2; ++p) {
            unsigned l0 = __shfl((int)pk0[2 * p], s0l), h0 = __shfl((int)pk0[2 * p + 1], s0l);
            unsigned l1 = __shfl((int)pk1[2 * p], s0l), h1 = __shfl((int)pk1[2 * p + 1], s0l);
            unsigned l2 = __shfl((int)pk0[2 * p], s1l), h2 = __shfl((int)pk0[2 * p + 1], s1l);
            unsigned l3 = __shfl((int)pk1[2 * p], s1l), h3 = __shfl((int)pk1[2 * p + 1], s1l);
            union { uintx4 u; short8 s; } bc;
            bc.u = (uintx4){hiq ? h0 : l0, hiq ? h1 : l1, hiq ? h2 : l2, hiq ? h3 : l3};
            bfr[p] = bc.s;
        }

        // ---- O^T += V^T P^T : A = Vt rows (b128), inline reads (r6 pattern) ----
        #pragma unroll
        for (int db = 0; db < 8; ++db) {
            int d = db * 16 + ln;
            short8 v0 = *(const short8*)&vs[d * BN + ((quad ^ (d & 7)) << 3)];
            short8 v1 = *(const short8*)&vs[d * BN + (((4 + quad) ^ (d & 7)) << 3)];
            o[db] = mfma16(v0, bfr[0], o[db]);
            o[db] = mfma16(v1, bfr[1], o[db]);
        }
    }

    // ---- epilogue: O = (O^T)^T / l ; lane ln owns qrow, regs are d ----
    {
        float inv = 1.f / l_i;
        size_t row = (size_t)bh * S_LEN + rowb0 + ln;
        float* orow = out + row * D_DIM + quad * 4;
        #pragma unroll
        for (int db = 0; db < 8; ++db) {
            float4 st = {o[db][0] * inv, o[db][1] * inv,
                         o[db][2] * inv, o[db][3] * inv};
            *(float4*)(orow + db * 16) = st;
        }
    }
}

extern "C" void kernel_launch(void* const* d_in, const int* in_sizes, int n_in,
                              void* d_out, int out_size, void* d_ws, size_t ws_size,
                              hipStream_t stream) {
    const float* q = (const float*)d_in[0];
    const float* k = (const float*)d_in[1];
    const float* v = (const float*)d_in[2];
    float* out = (float*)d_out;
    const int bh = in_sizes[0] / (S_LEN * D_DIM);     // 32
    const size_t kelems = (size_t)bh * S_LEN * D_DIM; // 8.39M

    u16* kw = (u16*)d_ws;
    u16* vt = kw + kelems;
    prep_kv<<<dim3(96, bh), 256, 0, stream>>>(k, v, kw, vt);
    fa_main<<<dim3(NQT * bh), 512, 0, stream>>>(q, kw, vt, out);
}